// Round 1
// baseline (670.802 us; speedup 1.0000x reference)
//
#include <hip/hip_runtime.h>
#include <math.h>

typedef __bf16 bf16x8 __attribute__((ext_vector_type(8)));
typedef float  f32x4  __attribute__((ext_vector_type(4)));

#define DEV __device__ __forceinline__

DEV void gload16(const void* g, void* l) {
  __builtin_amdgcn_global_load_lds(
      (const __attribute__((address_space(1))) void*)g,
      (__attribute__((address_space(3))) void*)l, 16, 0, 0);
}

// ---------------------------------------------------------------------------
// Weight f32 [R][C] -> bf16 [C][R] (transposed) so GEMMs take B^T row-major.
// ---------------------------------------------------------------------------
__global__ __launch_bounds__(256) void transpose_cvt(
    const float* __restrict__ in, __bf16* __restrict__ outT, int R, int C) {
  __shared__ float t[32][33];
  const int c0 = blockIdx.x * 32, r0 = blockIdx.y * 32;
  const int tx = threadIdx.x, ty = threadIdx.y;  // (32,8)
#pragma unroll
  for (int i = 0; i < 4; i++)
    t[ty + 8 * i][tx] = in[(size_t)(r0 + ty + 8 * i) * C + c0 + tx];
  __syncthreads();
#pragma unroll
  for (int i = 0; i < 4; i++)
    outT[(size_t)(c0 + ty + 8 * i) * R + r0 + tx] = (__bf16)t[tx][ty + 8 * i];
}

// ---------------------------------------------------------------------------
// RMSNorm row kernel: f32 [rows][2048] -> bf16, 1 block/row, 8 elems/thread.
// ---------------------------------------------------------------------------
__global__ __launch_bounds__(256) void rmsnorm_kernel(
    const float* __restrict__ x, const float* __restrict__ g, __bf16* __restrict__ out) {
  const int r = blockIdx.x, t = threadIdx.x;
  const float4* xr = (const float4*)(x + (size_t)r * 2048);
  float4 a = xr[2 * t], b = xr[2 * t + 1];
  float ss = a.x * a.x + a.y * a.y + a.z * a.z + a.w * a.w +
             b.x * b.x + b.y * b.y + b.z * b.z + b.w * b.w;
#pragma unroll
  for (int mk = 1; mk < 64; mk <<= 1) ss += __shfl_xor(ss, mk);
  __shared__ float red[4];
  if ((t & 63) == 0) red[t >> 6] = ss;
  __syncthreads();
  const float sc = rsqrtf((red[0] + red[1] + red[2] + red[3]) * (1.0f / 2048.0f) + 1e-6f);
  const float4* gr = (const float4*)g;
  float4 ga = gr[2 * t], gb = gr[2 * t + 1];
  bf16x8 ov;
  ov[0] = (__bf16)(a.x * sc * ga.x); ov[1] = (__bf16)(a.y * sc * ga.y);
  ov[2] = (__bf16)(a.z * sc * ga.z); ov[3] = (__bf16)(a.w * sc * ga.w);
  ov[4] = (__bf16)(b.x * sc * gb.x); ov[5] = (__bf16)(b.y * sc * gb.y);
  ov[6] = (__bf16)(b.z * sc * gb.z); ov[7] = (__bf16)(b.w * sc * gb.w);
  *(bf16x8*)(out + (size_t)r * 2048 + t * 8) = ov;
}

// ---------------------------------------------------------------------------
// GEMM: C[M][N] = A[M][K](bf16) @ BT[N][K](bf16)^T.  128x128 tile, BK=64,
// 4 waves (each 64x64 = 4x4 frags of 16x16), global_load_lds staging with
// XOR-swizzled LDS (slot ^= row&7 within 128B rows) on both store & read.
// EPI: 0 = bf16 store, 1 = f32 store + residual, 2 = gelu -> bf16.
// ---------------------------------------------------------------------------
template <int EPI>
__global__ __launch_bounds__(256) void gemm_bt(
    const __bf16* __restrict__ A, const __bf16* __restrict__ BT,
    void* __restrict__ Cout, const float* __restrict__ res, int M, int N, int K) {
  __shared__ char lds[32768];
  char* As = lds;
  char* Bs = lds + 16384;
  const int tid = threadIdx.x;
  const int lane = tid & 63;
  const int bn = blockIdx.x, bm = blockIdx.y;
  const int wm = tid >> 7, wn = (tid >> 6) & 1;

  f32x4 acc[4][4];
#pragma unroll
  for (int i = 0; i < 4; i++)
#pragma unroll
    for (int j = 0; j < 4; j++) acc[i][j] = (f32x4){0.f, 0.f, 0.f, 0.f};

  const size_t strideA = (size_t)K * 2;
  const char* ga[4];
  const char* gb[4];
#pragma unroll
  for (int t = 0; t < 4; t++) {
    int gg = t * 256 + tid;
    int row = gg >> 3, slot = gg & 7;
    ga[t] = (const char*)A + (size_t)(bm * 128 + row) * strideA + ((slot ^ (row & 7)) << 4);
    gb[t] = (const char*)BT + (size_t)(bn * 128 + row) * strideA + ((slot ^ (row & 7)) << 4);
  }

  for (int k0 = 0; k0 < K; k0 += 64) {
    __syncthreads();
#pragma unroll
    for (int t = 0; t < 4; t++) {
      int gg = t * 256 + tid;
      gload16(ga[t], As + gg * 16);
      gload16(gb[t], Bs + gg * 16);
      ga[t] += 128;
      gb[t] += 128;
    }
    __syncthreads();
#pragma unroll
    for (int kk = 0; kk < 2; kk++) {
      bf16x8 a[4], b[4];
      const int c16 = kk * 4 + (lane >> 4);
#pragma unroll
      for (int i = 0; i < 4; i++) {
        int ra = wm * 64 + i * 16 + (lane & 15);
        a[i] = *(const bf16x8*)(As + ra * 128 + ((c16 ^ (ra & 7)) << 4));
        int rb = wn * 64 + i * 16 + (lane & 15);
        b[i] = *(const bf16x8*)(Bs + rb * 128 + ((c16 ^ (rb & 7)) << 4));
      }
#pragma unroll
      for (int i = 0; i < 4; i++)
#pragma unroll
        for (int j = 0; j < 4; j++)
          acc[i][j] = __builtin_amdgcn_mfma_f32_16x16x32_bf16(a[i], b[j], acc[i][j], 0, 0, 0);
    }
  }

#pragma unroll
  for (int i = 0; i < 4; i++)
#pragma unroll
    for (int j = 0; j < 4; j++)
#pragma unroll
      for (int r = 0; r < 4; r++) {
        int row = bm * 128 + wm * 64 + i * 16 + ((lane >> 4) << 2) + r;
        int col = bn * 128 + wn * 64 + j * 16 + (lane & 15);
        size_t idx = (size_t)row * N + col;
        float v = acc[i][j][r];
        if (EPI == 0) {
          ((__bf16*)Cout)[idx] = (__bf16)v;
        } else if (EPI == 1) {
          ((float*)Cout)[idx] = v + res[idx];
        } else {
          float u = 0.7978845608028654f * (v + 0.044715f * v * v * v);
          ((__bf16*)Cout)[idx] = (__bf16)(0.5f * v * (1.0f + tanhf(u)));
        }
      }
}

// ---------------------------------------------------------------------------
// RoPE tables: cos/sin [2048][64] f32 (cos at [0], sin at +131072 elems).
// ---------------------------------------------------------------------------
__global__ __launch_bounds__(256) void rope_tables(float* __restrict__ tab) {
  const int idx = blockIdx.x * 256 + threadIdx.x;  // 131072
  const int s = idx >> 6, j = idx & 63;
  const float inv = powf(10000.0f, -(float)j / 64.0f);
  const float a = (float)s * inv;
  tab[idx] = cosf(a);
  tab[131072 + idx] = sinf(a);
}

// ---------------------------------------------------------------------------
// RoPE apply + head split: qkv bf16 [B*S][6144] -> q_r,k_r bf16 [B][H][S][128].
// One thread per (b,s,h,dpair), handles q and k.
// ---------------------------------------------------------------------------
__global__ __launch_bounds__(256) void rope_apply(
    const __bf16* __restrict__ qkv, const float* __restrict__ tab,
    __bf16* __restrict__ qr, __bf16* __restrict__ kr) {
  const int idx = blockIdx.x * 256 + threadIdx.x;  // 4194304
  const int j = idx & 63;
  const int h = (idx >> 6) & 15;
  const int s = (idx >> 10) & 2047;
  const int b = idx >> 21;
  const float c = tab[(s << 6) + j], sn = tab[131072 + (s << 6) + j];
  const size_t qi = ((size_t)(b * 2048 + s)) * 6144 + h * 128 + 2 * j;
  const size_t qo = ((size_t)((b * 16 + h) * 2048 + s)) * 128 + 2 * j;
  {
    float e = (float)qkv[qi], o = (float)qkv[qi + 1];
    qr[qo] = (__bf16)(e * c - o * sn);
    qr[qo + 1] = (__bf16)(o * c + e * sn);
  }
  {
    float e = (float)qkv[qi + 2048], o = (float)qkv[qi + 2048 + 1];
    kr[qo] = (__bf16)(e * c - o * sn);
    kr[qo + 1] = (__bf16)(o * c + e * sn);
  }
}

// ---------------------------------------------------------------------------
// V transpose: qkv v-part [B*S][6144] -> vt bf16 [B][H][128][S].
// ---------------------------------------------------------------------------
__global__ __launch_bounds__(256) void v_transpose(
    const __bf16* __restrict__ qkv, __bf16* __restrict__ vt) {
  __shared__ __bf16 t[32][33];
  const int s0 = blockIdx.x * 32, d0 = blockIdx.y * 32, bh = blockIdx.z;
  const int b = bh >> 4, h = bh & 15;
  const int tx = threadIdx.x, ty = threadIdx.y;  // (32,8)
#pragma unroll
  for (int i = 0; i < 4; i++)
    t[ty + 8 * i][tx] =
        qkv[((size_t)(b * 2048 + s0 + ty + 8 * i)) * 6144 + 4096 + h * 128 + d0 + tx];
  __syncthreads();
#pragma unroll
  for (int i = 0; i < 4; i++)
    vt[((size_t)bh * 128 + d0 + ty + 8 * i) * 2048 + s0 + tx] = t[tx][ty + 8 * i];
}

// ---------------------------------------------------------------------------
// Flash attention (causal). Block = (qtile of 64, h, b); 4 waves x 16 q-rows.
// KV tile = 64 positions. K LDS [64][128] (16-slot swizzle), V^T LDS [128][64]
// (8-slot swizzle), per-wave P buffer [16][64] (8-slot swizzle).
// ---------------------------------------------------------------------------
__global__ __launch_bounds__(256) void flash_attn(
    const __bf16* __restrict__ qg, const __bf16* __restrict__ kg,
    const __bf16* __restrict__ vtg, __bf16* __restrict__ og) {
  __shared__ char lds[40960];
  char* Ks = lds;
  char* Vs = lds + 16384;
  char* Ps = lds + 32768;
  const int tid = threadIdx.x, lane = tid & 63, w = tid >> 6;
  const int qt = blockIdx.x, h = blockIdx.y, b = blockIdx.z;
  const int bh = b * 16 + h;
  const __bf16* qb = qg + (size_t)bh * 2048 * 128;
  const __bf16* kb = kg + (size_t)bh * 2048 * 128;
  const __bf16* vb = vtg + (size_t)bh * 128 * 2048;
  const int qrow0 = qt * 64 + w * 16;

  bf16x8 qf[4];
#pragma unroll
  for (int c = 0; c < 4; c++)
    qf[c] = *(const bf16x8*)(qb + (size_t)(qrow0 + (lane & 15)) * 128 + c * 32 + ((lane >> 4) << 3));

  float m[4], ls[4];
  f32x4 o[8];
#pragma unroll
  for (int r = 0; r < 4; r++) { m[r] = -__builtin_inff(); ls[r] = 0.f; }
#pragma unroll
  for (int n = 0; n < 8; n++) o[n] = (f32x4){0.f, 0.f, 0.f, 0.f};
  const float scale = 0.08838834764831845f;  // 1/sqrt(128)

  for (int kt = 0; kt <= qt; kt++) {
    __syncthreads();
#pragma unroll
    for (int t = 0; t < 4; t++) {
      int gg = t * 256 + tid;
      int rk = gg >> 4, sk = gg & 15;
      gload16((const char*)(kb + (size_t)(kt * 64 + rk) * 128) + ((sk ^ (rk & 15)) << 4),
              Ks + gg * 16);
      int rv = gg >> 3, sv = gg & 7;
      gload16((const char*)(vb + (size_t)rv * 2048 + kt * 64) + ((sv ^ (rv & 7)) << 4),
              Vs + gg * 16);
    }
    __syncthreads();

    f32x4 s[4];
#pragma unroll
    for (int n = 0; n < 4; n++) {
      s[n] = (f32x4){0.f, 0.f, 0.f, 0.f};
#pragma unroll
      for (int c = 0; c < 4; c++) {
        int krow = n * 16 + (lane & 15);
        int c16 = c * 4 + (lane >> 4);
        bf16x8 kf = *(const bf16x8*)(Ks + krow * 256 + ((c16 ^ (krow & 15)) << 4));
        s[n] = __builtin_amdgcn_mfma_f32_16x16x32_bf16(qf[c], kf, s[n], 0, 0, 0);
      }
    }

    float p[4][4], fc[4];
#pragma unroll
    for (int r = 0; r < 4; r++) {
      const int qrow = qrow0 + ((lane >> 4) << 2) + r;
#pragma unroll
      for (int n = 0; n < 4; n++) {
        int col = kt * 64 + n * 16 + (lane & 15);
        if (col > qrow) s[n][r] = -__builtin_inff();
      }
      float tmx = fmaxf(fmaxf(s[0][r], s[1][r]), fmaxf(s[2][r], s[3][r]));
#pragma unroll
      for (int mk = 1; mk < 16; mk <<= 1) tmx = fmaxf(tmx, __shfl_xor(tmx, mk));
      float nm = fmaxf(m[r], tmx);
      fc[r] = expf(scale * (m[r] - nm));
      float sum = 0.f;
#pragma unroll
      for (int n = 0; n < 4; n++) {
        float pv = expf(scale * (s[n][r] - nm));
        p[n][r] = pv;
        sum += pv;
      }
#pragma unroll
      for (int mk = 1; mk < 16; mk <<= 1) sum += __shfl_xor(sum, mk);
      ls[r] = ls[r] * fc[r] + sum;
      m[r] = nm;
    }
#pragma unroll
    for (int n = 0; n < 8; n++) {
      o[n][0] *= fc[0]; o[n][1] *= fc[1]; o[n][2] *= fc[2]; o[n][3] *= fc[3];
    }

    char* Pw = Ps + w * 2048;
#pragma unroll
    for (int n = 0; n < 4; n++)
#pragma unroll
      for (int r = 0; r < 4; r++) {
        int prow = ((lane >> 4) << 2) + r;
        int col = n * 16 + (lane & 15);
        int ch = col >> 3;
        *(__bf16*)(Pw + prow * 128 + ((ch ^ (prow & 7)) << 4) + ((col & 7) << 1)) =
            (__bf16)p[n][r];
      }

#pragma unroll
    for (int kk = 0; kk < 2; kk++) {
      int prow = lane & 15;
      int pc = kk * 4 + (lane >> 4);
      bf16x8 pf = *(const bf16x8*)(Pw + prow * 128 + ((pc ^ (prow & 7)) << 4));
#pragma unroll
      for (int n = 0; n < 8; n++) {
        int vr = n * 16 + (lane & 15);
        bf16x8 vf = *(const bf16x8*)(Vs + vr * 128 + ((pc ^ (vr & 7)) << 4));
        o[n] = __builtin_amdgcn_mfma_f32_16x16x32_bf16(pf, vf, o[n], 0, 0, 0);
      }
    }
  }

#pragma unroll
  for (int n = 0; n < 8; n++)
#pragma unroll
    for (int r = 0; r < 4; r++) {
      int qrow = qrow0 + ((lane >> 4) << 2) + r;
      og[(size_t)(b * 2048 + qrow) * 2048 + h * 128 + n * 16 + (lane & 15)] =
          (__bf16)(o[n][r] / ls[r]);
    }
}

// ---------------------------------------------------------------------------
extern "C" void kernel_launch(void* const* d_in, const int* in_sizes, int n_in,
                              void* d_out, int out_size, void* d_ws, size_t ws_size,
                              hipStream_t stream) {
  const float* x = (const float*)d_in[0];
  const float* w_qkv = (const float*)d_in[1];
  const float* w_out = (const float*)d_in[2];
  const float* w_fc = (const float*)d_in[3];
  const float* w_proj = (const float*)d_in[4];
  const float* g_in = (const float*)d_in[5];
  const float* g_ff = (const float*)d_in[6];
  float* out = (float*)d_out;
  char* ws = (char*)d_ws;

  // workspace layout (bytes) — total 236 MB
  constexpr size_t O_WQKV = 0;           // bf16 [6144][2048]
  constexpr size_t O_WOUT = 25165824;    // bf16 [2048][2048]
  constexpr size_t O_WFC = 33554432;     // bf16 [4096][2048]
  constexpr size_t O_WPROJ = 50331648;   // bf16 [2048][4096]
  constexpr size_t O_H = 67108864;       // bf16 [4096][2048]   (h, then h2)
  constexpr size_t O_QKV = 83886080;     // bf16 [4096][6144]   (later: fcact [4096][4096])
  constexpr size_t O_Q = 134217728;      // bf16 [2][16][2048][128]
  constexpr size_t O_K = 150994944;
  constexpr size_t O_VT = 167772160;     // bf16 [2][16][128][2048]
  constexpr size_t O_TAB = 184549376;    // f32 cos/sin [2][2048][64]
  constexpr size_t O_ATTN = 185597952;   // bf16 [4096][2048]
  constexpr size_t O_X1 = 202375168;     // f32 [4096][2048]

  __bf16* wqkvT = (__bf16*)(ws + O_WQKV);
  __bf16* woutT = (__bf16*)(ws + O_WOUT);
  __bf16* wfcT = (__bf16*)(ws + O_WFC);
  __bf16* wprojT = (__bf16*)(ws + O_WPROJ);
  __bf16* h = (__bf16*)(ws + O_H);
  __bf16* qkv = (__bf16*)(ws + O_QKV);
  __bf16* fcact = (__bf16*)(ws + O_QKV);
  __bf16* qr = (__bf16*)(ws + O_Q);
  __bf16* kr = (__bf16*)(ws + O_K);
  __bf16* vt = (__bf16*)(ws + O_VT);
  float* tab = (float*)(ws + O_TAB);
  __bf16* attn = (__bf16*)(ws + O_ATTN);
  float* x1 = (float*)(ws + O_X1);

  const dim3 tb(32, 8);
  // weight convert+transpose
  transpose_cvt<<<dim3(6144 / 32, 2048 / 32), tb, 0, stream>>>(w_qkv, wqkvT, 2048, 6144);
  transpose_cvt<<<dim3(2048 / 32, 2048 / 32), tb, 0, stream>>>(w_out, woutT, 2048, 2048);
  transpose_cvt<<<dim3(4096 / 32, 2048 / 32), tb, 0, stream>>>(w_fc, wfcT, 2048, 4096);
  transpose_cvt<<<dim3(2048 / 32, 4096 / 32), tb, 0, stream>>>(w_proj, wprojT, 4096, 2048);

  // h = rmsnorm(x, g_in)
  rmsnorm_kernel<<<4096, 256, 0, stream>>>(x, g_in, h);
  // qkv = h @ w_qkv
  gemm_bt<0><<<dim3(48, 32), 256, 0, stream>>>(h, wqkvT, (void*)qkv, nullptr, 4096, 6144, 2048);
  // rope
  rope_tables<<<512, 256, 0, stream>>>(tab);
  rope_apply<<<16384, 256, 0, stream>>>(qkv, tab, qr, kr);
  v_transpose<<<dim3(64, 4, 32), tb, 0, stream>>>(qkv, vt);
  // attention
  flash_attn<<<dim3(32, 16, 2), 256, 0, stream>>>(qr, kr, vt, attn);
  // x1 = x + attn @ w_out
  gemm_bt<1><<<dim3(16, 32), 256, 0, stream>>>(attn, woutT, (void*)x1, x, 4096, 2048, 2048);
  // h2 = rmsnorm(x1, g_ff)
  rmsnorm_kernel<<<4096, 256, 0, stream>>>(x1, g_ff, h);
  // fcact = gelu(h2 @ w_fc)
  gemm_bt<2><<<dim3(32, 32), 256, 0, stream>>>(h, wfcT, (void*)fcact, nullptr, 4096, 4096, 2048);
  // out = x1 + fcact @ w_proj
  gemm_bt<1><<<dim3(16, 32), 256, 0, stream>>>(fcact, wprojT, (void*)out, x1, 4096, 2048, 4096);
}

// Round 2
// 551.604 us; speedup vs baseline: 1.2161x; 1.2161x over previous
//
#include <hip/hip_runtime.h>
#include <math.h>

typedef __bf16 bf16x8 __attribute__((ext_vector_type(8)));
typedef float  f32x4  __attribute__((ext_vector_type(4)));

#define DEV __device__ __forceinline__

DEV void gload16(const void* g, void* l) {
  __builtin_amdgcn_global_load_lds(
      (const __attribute__((address_space(1))) void*)g,
      (__attribute__((address_space(3))) void*)l, 16, 0, 0);
}

// ---------------------------------------------------------------------------
// Weight f32 [R][C] -> bf16 [C][R] (transposed) so GEMMs take B^T row-major.
// ---------------------------------------------------------------------------
__global__ __launch_bounds__(256) void transpose_cvt(
    const float* __restrict__ in, __bf16* __restrict__ outT, int R, int C) {
  __shared__ float t[32][33];
  const int c0 = blockIdx.x * 32, r0 = blockIdx.y * 32;
  const int tx = threadIdx.x, ty = threadIdx.y;  // (32,8)
#pragma unroll
  for (int i = 0; i < 4; i++)
    t[ty + 8 * i][tx] = in[(size_t)(r0 + ty + 8 * i) * C + c0 + tx];
  __syncthreads();
#pragma unroll
  for (int i = 0; i < 4; i++)
    outT[(size_t)(c0 + ty + 8 * i) * R + r0 + tx] = (__bf16)t[tx][ty + 8 * i];
}

// ---------------------------------------------------------------------------
// RMSNorm row kernel: f32 [rows][2048] -> bf16, 1 block/row, 8 elems/thread.
// ---------------------------------------------------------------------------
__global__ __launch_bounds__(256) void rmsnorm_kernel(
    const float* __restrict__ x, const float* __restrict__ g, __bf16* __restrict__ out) {
  const int r = blockIdx.x, t = threadIdx.x;
  const float4* xr = (const float4*)(x + (size_t)r * 2048);
  float4 a = xr[2 * t], b = xr[2 * t + 1];
  float ss = a.x * a.x + a.y * a.y + a.z * a.z + a.w * a.w +
             b.x * b.x + b.y * b.y + b.z * b.z + b.w * b.w;
#pragma unroll
  for (int mk = 1; mk < 64; mk <<= 1) ss += __shfl_xor(ss, mk);
  __shared__ float red[4];
  if ((t & 63) == 0) red[t >> 6] = ss;
  __syncthreads();
  const float sc = rsqrtf((red[0] + red[1] + red[2] + red[3]) * (1.0f / 2048.0f) + 1e-6f);
  const float4* gr = (const float4*)g;
  float4 ga = gr[2 * t], gb = gr[2 * t + 1];
  bf16x8 ov;
  ov[0] = (__bf16)(a.x * sc * ga.x); ov[1] = (__bf16)(a.y * sc * ga.y);
  ov[2] = (__bf16)(a.z * sc * ga.z); ov[3] = (__bf16)(a.w * sc * ga.w);
  ov[4] = (__bf16)(b.x * sc * gb.x); ov[5] = (__bf16)(b.y * sc * gb.y);
  ov[6] = (__bf16)(b.z * sc * gb.z); ov[7] = (__bf16)(b.w * sc * gb.w);
  *(bf16x8*)(out + (size_t)r * 2048 + t * 8) = ov;
}

// ---------------------------------------------------------------------------
// GEMM: C[M][N] = A[M][K](bf16) @ BT[N][K](bf16)^T.  128x128 tile, BK=64,
// 4 waves (each 64x64 = 4x4 frags of 16x16), global_load_lds staging with
// XOR-swizzled LDS (slot ^= row&7 within 128B rows) on both store & read.
// EPI: 0 = bf16 store, 1 = f32 store + residual, 2 = gelu -> bf16.
// ---------------------------------------------------------------------------
template <int EPI>
__global__ __launch_bounds__(256) void gemm_bt(
    const __bf16* __restrict__ A, const __bf16* __restrict__ BT,
    void* __restrict__ Cout, const float* __restrict__ res, int M, int N, int K) {
  __shared__ char lds[32768];
  char* As = lds;
  char* Bs = lds + 16384;
  const int tid = threadIdx.x;
  const int lane = tid & 63;
  const int bn = blockIdx.x, bm = blockIdx.y;
  const int wm = tid >> 7, wn = (tid >> 6) & 1;

  f32x4 acc[4][4];
#pragma unroll
  for (int i = 0; i < 4; i++)
#pragma unroll
    for (int j = 0; j < 4; j++) acc[i][j] = (f32x4){0.f, 0.f, 0.f, 0.f};

  const size_t strideA = (size_t)K * 2;
  const char* ga[4];
  const char* gb[4];
#pragma unroll
  for (int t = 0; t < 4; t++) {
    int gg = t * 256 + tid;
    int row = gg >> 3, slot = gg & 7;
    ga[t] = (const char*)A + (size_t)(bm * 128 + row) * strideA + ((slot ^ (row & 7)) << 4);
    gb[t] = (const char*)BT + (size_t)(bn * 128 + row) * strideA + ((slot ^ (row & 7)) << 4);
  }

  for (int k0 = 0; k0 < K; k0 += 64) {
    __syncthreads();
#pragma unroll
    for (int t = 0; t < 4; t++) {
      int gg = t * 256 + tid;
      gload16(ga[t], As + gg * 16);
      gload16(gb[t], Bs + gg * 16);
      ga[t] += 128;
      gb[t] += 128;
    }
    __syncthreads();
#pragma unroll
    for (int kk = 0; kk < 2; kk++) {
      bf16x8 a[4], b[4];
      const int c16 = kk * 4 + (lane >> 4);
#pragma unroll
      for (int i = 0; i < 4; i++) {
        int ra = wm * 64 + i * 16 + (lane & 15);
        a[i] = *(const bf16x8*)(As + ra * 128 + ((c16 ^ (ra & 7)) << 4));
        int rb = wn * 64 + i * 16 + (lane & 15);
        b[i] = *(const bf16x8*)(Bs + rb * 128 + ((c16 ^ (rb & 7)) << 4));
      }
#pragma unroll
      for (int i = 0; i < 4; i++)
#pragma unroll
        for (int j = 0; j < 4; j++)
          acc[i][j] = __builtin_amdgcn_mfma_f32_16x16x32_bf16(a[i], b[j], acc[i][j], 0, 0, 0);
    }
  }

#pragma unroll
  for (int i = 0; i < 4; i++)
#pragma unroll
    for (int j = 0; j < 4; j++)
#pragma unroll
      for (int r = 0; r < 4; r++) {
        int row = bm * 128 + wm * 64 + i * 16 + ((lane >> 4) << 2) + r;
        int col = bn * 128 + wn * 64 + j * 16 + (lane & 15);
        size_t idx = (size_t)row * N + col;
        float v = acc[i][j][r];
        if (EPI == 0) {
          ((__bf16*)Cout)[idx] = (__bf16)v;
        } else if (EPI == 1) {
          ((float*)Cout)[idx] = v + res[idx];
        } else {
          float u = 0.7978845608028654f * (v + 0.044715f * v * v * v);
          ((__bf16*)Cout)[idx] = (__bf16)(0.5f * v * (1.0f + tanhf(u)));
        }
      }
}

// ---------------------------------------------------------------------------
// RoPE tables: cos/sin [2048][64] f32 (cos at [0], sin at +131072 elems).
// ---------------------------------------------------------------------------
__global__ __launch_bounds__(256) void rope_tables(float* __restrict__ tab) {
  const int idx = blockIdx.x * 256 + threadIdx.x;  // 131072
  const int s = idx >> 6, j = idx & 63;
  const float inv = powf(10000.0f, -(float)j / 64.0f);
  const float a = (float)s * inv;
  tab[idx] = cosf(a);
  tab[131072 + idx] = sinf(a);
}

// ---------------------------------------------------------------------------
// RoPE apply + head split: qkv bf16 [B*S][6144] -> q_r,k_r bf16 [B][H][S][128].
// ---------------------------------------------------------------------------
__global__ __launch_bounds__(256) void rope_apply(
    const __bf16* __restrict__ qkv, const float* __restrict__ tab,
    __bf16* __restrict__ qr, __bf16* __restrict__ kr) {
  const int idx = blockIdx.x * 256 + threadIdx.x;  // 4194304
  const int j = idx & 63;
  const int h = (idx >> 6) & 15;
  const int s = (idx >> 10) & 2047;
  const int b = idx >> 21;
  const float c = tab[(s << 6) + j], sn = tab[131072 + (s << 6) + j];
  const size_t qi = ((size_t)(b * 2048 + s)) * 6144 + h * 128 + 2 * j;
  const size_t qo = ((size_t)((b * 16 + h) * 2048 + s)) * 128 + 2 * j;
  {
    float e = (float)qkv[qi], o = (float)qkv[qi + 1];
    qr[qo] = (__bf16)(e * c - o * sn);
    qr[qo + 1] = (__bf16)(o * c + e * sn);
  }
  {
    float e = (float)qkv[qi + 2048], o = (float)qkv[qi + 2048 + 1];
    kr[qo] = (__bf16)(e * c - o * sn);
    kr[qo + 1] = (__bf16)(o * c + e * sn);
  }
}

// ---------------------------------------------------------------------------
// V transpose: qkv v-part [B*S][6144] -> vt bf16 [B][H][128][S].
// ---------------------------------------------------------------------------
__global__ __launch_bounds__(256) void v_transpose(
    const __bf16* __restrict__ qkv, __bf16* __restrict__ vt) {
  __shared__ __bf16 t[32][33];
  const int s0 = blockIdx.x * 32, d0 = blockIdx.y * 32, bh = blockIdx.z;
  const int b = bh >> 4, h = bh & 15;
  const int tx = threadIdx.x, ty = threadIdx.y;  // (32,8)
#pragma unroll
  for (int i = 0; i < 4; i++)
    t[ty + 8 * i][tx] =
        qkv[((size_t)(b * 2048 + s0 + ty + 8 * i)) * 6144 + 4096 + h * 128 + d0 + tx];
  __syncthreads();
#pragma unroll
  for (int i = 0; i < 4; i++)
    vt[((size_t)bh * 128 + d0 + ty + 8 * i) * 2048 + s0 + tx] = t[tx][ty + 8 * i];
}

// ---------------------------------------------------------------------------
// Flash attention (causal), load-balanced + pipelined.
// Grid (16,16,2): block runs q-tiles (31-bx) then (bx) -> uniform 33 KV tiles.
// 4 waves x 16 q-rows, KV tile = 64. Double-buffered K[64][128] (16-slot
// swizzle) / V^T[128][64] (8-slot swizzle), 2-phase prefetch with counted
// vmcnt, exp2-domain softmax with deferred max (THR=8), diag-only masking.
// LDS: K 2x16K | V 2x16K | P 4x2K = 73728 B -> 2 blocks/CU.
// ---------------------------------------------------------------------------
__global__ __launch_bounds__(256) void flash_attn(
    const __bf16* __restrict__ qg, const __bf16* __restrict__ kg,
    const __bf16* __restrict__ vtg, __bf16* __restrict__ og) {
  __shared__ char lds[73728];
  const int tid = threadIdx.x, lane = tid & 63, w = tid >> 6;
  const int h = blockIdx.y, b = blockIdx.z;
  const int bh = b * 16 + h;
  const __bf16* qb = qg + (size_t)bh * 2048 * 128;
  const char* kbb = (const char*)(kg + (size_t)bh * 2048 * 128);
  const char* vbb = (const char*)(vtg + (size_t)bh * 128 * 2048);
  char* Pw = lds + 65536 + w * 2048;

  // per-thread staging source addresses (tile 0); K tile stride 16384 B,
  // V tile stride 128 B (columns within [128][2048] rows).
  const char* gK[4];
  const char* gV[4];
#pragma unroll
  for (int t = 0; t < 4; t++) {
    int gg = t * 256 + tid;
    int rk = gg >> 4, sk = gg & 15;
    gK[t] = kbb + rk * 256 + ((sk ^ (rk & 15)) << 4);
    int rv = gg >> 3, sv = gg & 7;
    gV[t] = vbb + rv * 4096 + ((sv ^ (rv & 7)) << 4);
  }

  const float SL2E = 0.08838834764831845f * 1.4426950408889634f;  // scale*log2(e)

  auto run_qtile = [&](int qt) {
    const int qrow0 = qt * 64 + w * 16;
    bf16x8 qf[4];
#pragma unroll
    for (int c = 0; c < 4; c++) {
      bf16x8 raw = *(const bf16x8*)(qb + (size_t)(qrow0 + (lane & 15)) * 128 +
                                    c * 32 + ((lane >> 4) << 3));
#pragma unroll
      for (int e = 0; e < 8; e++) qf[c][e] = (__bf16)((float)raw[e] * SL2E);
    }
    float m[4], ls[4];
    f32x4 o[8];
#pragma unroll
    for (int r = 0; r < 4; r++) { m[r] = -__builtin_inff(); ls[r] = 0.f; }
#pragma unroll
    for (int n = 0; n < 8; n++) o[n] = (f32x4){0.f, 0.f, 0.f, 0.f};

    // stage tile 0 -> buffer 0 (8 loads/thread outstanding)
#pragma unroll
    for (int t = 0; t < 4; t++) {
      int gg = t * 256 + tid;
      gload16(gK[t], lds + gg * 16);
      gload16(gV[t], lds + 32768 + gg * 16);
    }

    for (int kt = 0; kt <= qt; kt++) {
      const int cur = kt & 1;
      char* Ks = lds + cur * 16384;
      char* Vs = lds + 32768 + cur * 16384;
      if (kt < qt) {
        char* Kd = lds + (cur ^ 1) * 16384;
        char* Vd = lds + 32768 + (cur ^ 1) * 16384;
#pragma unroll
        for (int t = 0; t < 4; t++) {
          int gg = t * 256 + tid;
          gload16(gK[t] + (size_t)(kt + 1) * 16384, Kd + gg * 16);
          gload16(gV[t] + (size_t)(kt + 1) * 128, Vd + gg * 16);
        }
        asm volatile("s_waitcnt vmcnt(8)" ::: "memory");  // current tile landed
      } else {
        asm volatile("s_waitcnt vmcnt(0)" ::: "memory");
      }
      __builtin_amdgcn_s_barrier();

      // QK^T (pre-scaled Q -> s is in log2 domain)
      f32x4 s[4];
      __builtin_amdgcn_s_setprio(1);
#pragma unroll
      for (int n = 0; n < 4; n++) {
        s[n] = (f32x4){0.f, 0.f, 0.f, 0.f};
#pragma unroll
        for (int c = 0; c < 4; c++) {
          int krow = n * 16 + (lane & 15);
          int c16 = c * 4 + (lane >> 4);
          bf16x8 kf = *(const bf16x8*)(Ks + krow * 256 + ((c16 ^ (krow & 15)) << 4));
          s[n] = __builtin_amdgcn_mfma_f32_16x16x32_bf16(qf[c], kf, s[n], 0, 0, 0);
        }
      }
      __builtin_amdgcn_s_setprio(0);

      float p[4][4], fc[4];
      const bool diag = (kt == qt);
#pragma unroll
      for (int r = 0; r < 4; r++) {
        if (diag) {
          const int qrow = qrow0 + ((lane >> 4) << 2) + r;
#pragma unroll
          for (int n = 0; n < 4; n++) {
            int col = kt * 64 + n * 16 + (lane & 15);
            if (col > qrow) s[n][r] = -__builtin_inff();
          }
        }
        float tmx = fmaxf(fmaxf(s[0][r], s[1][r]), fmaxf(s[2][r], s[3][r]));
#pragma unroll
        for (int mk = 1; mk < 16; mk <<= 1) tmx = fmaxf(tmx, __shfl_xor(tmx, mk));
        float nm;
        if (tmx <= m[r] + 8.f) {  // deferred max: p bounded by 2^8, exact math
          nm = m[r];
          fc[r] = 1.f;
        } else {
          nm = tmx;
          fc[r] = exp2f(m[r] - nm);
          m[r] = nm;
        }
        float sum = 0.f;
#pragma unroll
        for (int n = 0; n < 4; n++) {
          float pv = exp2f(s[n][r] - nm);
          p[n][r] = pv;
          sum += pv;
        }
#pragma unroll
        for (int mk = 1; mk < 16; mk <<= 1) sum += __shfl_xor(sum, mk);
        ls[r] = ls[r] * fc[r] + sum;
      }
      if ((fc[0] < 1.f) | (fc[1] < 1.f) | (fc[2] < 1.f) | (fc[3] < 1.f)) {
#pragma unroll
        for (int n = 0; n < 8; n++) {
          o[n][0] *= fc[0]; o[n][1] *= fc[1]; o[n][2] *= fc[2]; o[n][3] *= fc[3];
        }
      }

      // P -> per-wave swizzled LDS -> A-fragments
#pragma unroll
      for (int n = 0; n < 4; n++)
#pragma unroll
        for (int r = 0; r < 4; r++) {
          int prow = ((lane >> 4) << 2) + r;
          int col = n * 16 + (lane & 15);
          int ch = col >> 3;
          *(__bf16*)(Pw + prow * 128 + ((ch ^ (prow & 7)) << 4) + ((col & 7) << 1)) =
              (__bf16)p[n][r];
        }

      __builtin_amdgcn_s_setprio(1);
#pragma unroll
      for (int kk = 0; kk < 2; kk++) {
        int prow = lane & 15;
        int pc = kk * 4 + (lane >> 4);
        bf16x8 pf = *(const bf16x8*)(Pw + prow * 128 + ((pc ^ (prow & 7)) << 4));
#pragma unroll
        for (int n = 0; n < 8; n++) {
          int vr = n * 16 + (lane & 15);
          bf16x8 vf = *(const bf16x8*)(Vs + vr * 128 + ((pc ^ (vr & 7)) << 4));
          o[n] = __builtin_amdgcn_mfma_f32_16x16x32_bf16(pf, vf, o[n], 0, 0, 0);
        }
      }
      __builtin_amdgcn_s_setprio(0);
      __builtin_amdgcn_s_barrier();  // all reads of cur done before overwrite
    }

    float inv[4];
#pragma unroll
    for (int r = 0; r < 4; r++) inv[r] = 1.0f / ls[r];
#pragma unroll
    for (int n = 0; n < 8; n++)
#pragma unroll
      for (int r = 0; r < 4; r++) {
        int qrow = qrow0 + ((lane >> 4) << 2) + r;
        og[(size_t)(b * 2048 + qrow) * 2048 + h * 128 + n * 16 + (lane & 15)] =
            (__bf16)(o[n][r] * inv[r]);
      }
  };

  run_qtile(31 - (int)blockIdx.x);
  run_qtile((int)blockIdx.x);
}

// ---------------------------------------------------------------------------
extern "C" void kernel_launch(void* const* d_in, const int* in_sizes, int n_in,
                              void* d_out, int out_size, void* d_ws, size_t ws_size,
                              hipStream_t stream) {
  const float* x = (const float*)d_in[0];
  const float* w_qkv = (const float*)d_in[1];
  const float* w_out = (const float*)d_in[2];
  const float* w_fc = (const float*)d_in[3];
  const float* w_proj = (const float*)d_in[4];
  const float* g_in = (const float*)d_in[5];
  const float* g_ff = (const float*)d_in[6];
  float* out = (float*)d_out;
  char* ws = (char*)d_ws;

  // workspace layout (bytes) — total 236 MB
  constexpr size_t O_WQKV = 0;           // bf16 [6144][2048]
  constexpr size_t O_WOUT = 25165824;    // bf16 [2048][2048]
  constexpr size_t O_WFC = 33554432;     // bf16 [4096][2048]
  constexpr size_t O_WPROJ = 50331648;   // bf16 [2048][4096]
  constexpr size_t O_H = 67108864;       // bf16 [4096][2048]   (h, then h2)
  constexpr size_t O_QKV = 83886080;     // bf16 [4096][6144]   (later: fcact [4096][4096])
  constexpr size_t O_Q = 134217728;      // bf16 [2][16][2048][128]
  constexpr size_t O_K = 150994944;
  constexpr size_t O_VT = 167772160;     // bf16 [2][16][128][2048]
  constexpr size_t O_TAB = 184549376;    // f32 cos/sin [2][2048][64]
  constexpr size_t O_ATTN = 185597952;   // bf16 [4096][2048]
  constexpr size_t O_X1 = 202375168;     // f32 [4096][2048]

  __bf16* wqkvT = (__bf16*)(ws + O_WQKV);
  __bf16* woutT = (__bf16*)(ws + O_WOUT);
  __bf16* wfcT = (__bf16*)(ws + O_WFC);
  __bf16* wprojT = (__bf16*)(ws + O_WPROJ);
  __bf16* h = (__bf16*)(ws + O_H);
  __bf16* qkv = (__bf16*)(ws + O_QKV);
  __bf16* fcact = (__bf16*)(ws + O_QKV);
  __bf16* qr = (__bf16*)(ws + O_Q);
  __bf16* kr = (__bf16*)(ws + O_K);
  __bf16* vt = (__bf16*)(ws + O_VT);
  float* tab = (float*)(ws + O_TAB);
  __bf16* attn = (__bf16*)(ws + O_ATTN);
  float* x1 = (float*)(ws + O_X1);

  const dim3 tb(32, 8);
  // weight convert+transpose
  transpose_cvt<<<dim3(6144 / 32, 2048 / 32), tb, 0, stream>>>(w_qkv, wqkvT, 2048, 6144);
  transpose_cvt<<<dim3(2048 / 32, 2048 / 32), tb, 0, stream>>>(w_out, woutT, 2048, 2048);
  transpose_cvt<<<dim3(4096 / 32, 2048 / 32), tb, 0, stream>>>(w_fc, wfcT, 2048, 4096);
  transpose_cvt<<<dim3(2048 / 32, 4096 / 32), tb, 0, stream>>>(w_proj, wprojT, 4096, 2048);

  // h = rmsnorm(x, g_in)
  rmsnorm_kernel<<<4096, 256, 0, stream>>>(x, g_in, h);
  // qkv = h @ w_qkv
  gemm_bt<0><<<dim3(48, 32), 256, 0, stream>>>(h, wqkvT, (void*)qkv, nullptr, 4096, 6144, 2048);
  // rope
  rope_tables<<<512, 256, 0, stream>>>(tab);
  rope_apply<<<16384, 256, 0, stream>>>(qkv, tab, qr, kr);
  v_transpose<<<dim3(64, 4, 32), tb, 0, stream>>>(qkv, vt);
  // attention (load-balanced pairs)
  flash_attn<<<dim3(16, 16, 2), 256, 0, stream>>>(qr, kr, vt, attn);
  // x1 = x + attn @ w_out
  gemm_bt<1><<<dim3(16, 32), 256, 0, stream>>>(attn, woutT, (void*)x1, x, 4096, 2048, 2048);
  // h2 = rmsnorm(x1, g_ff)
  rmsnorm_kernel<<<4096, 256, 0, stream>>>(x1, g_ff, h);
  // fcact = gelu(h2 @ w_fc)
  gemm_bt<2><<<dim3(32, 32), 256, 0, stream>>>(h, wfcT, (void*)fcact, nullptr, 4096, 4096, 2048);
  // out = x1 + fcact @ w_proj
  gemm_bt<1><<<dim3(16, 32), 256, 0, stream>>>(fcact, wprojT, (void*)out, x1, 4096, 2048, 4096);
}